// Round 1
// baseline (810.482 us; speedup 1.0000x reference)
//
#include <hip/hip_runtime.h>
#include <cstdint>
#include <cstddef>

// ---------------------------------------------------------------------------
// GCN+LPA: h = relu(spmm(x@w1)+b1); out0 = sigmoid(spmm(h@w2)+b2)
//          out1 = sigmoid(spmm^5(soft_labels))
// spmm uses row-normalized weighted adjacency: val[e] = edge_attr[e]/deg[row[e]]
// Strategy: build CSR once (atomic counts -> scan -> atomic fill), then
// one-wave-per-row gather SpMM (no float atomics), LDS-tiled f32 GEMMs.
// ---------------------------------------------------------------------------

#define WS_ALIGN(x) (((x) + 255) & ~((size_t)255))

__global__ void deg_count_kernel(const int* __restrict__ row, const float* __restrict__ ea,
                                 float* __restrict__ deg, int* __restrict__ cnt, int E)
{
    int e = blockIdx.x * 256 + threadIdx.x;
    if (e < E) {
        int r = row[e];
        atomicAdd(&deg[r], ea[e]);
        atomicAdd(&cnt[r], 1);
    }
}

// block scans 1024 counts (4/thread), writes exclusive-in-block prefix + block total
__global__ void scan_block_kernel(const int* __restrict__ cnt, int* __restrict__ exc,
                                  int* __restrict__ partials, int n)
{
    __shared__ int sdata[256];
    const int tid = threadIdx.x;
    const int base = blockIdx.x * 1024;
    int v[4];
    int sum = 0;
#pragma unroll
    for (int j = 0; j < 4; ++j) {
        int idx = base + tid * 4 + j;
        v[j] = (idx < n) ? cnt[idx] : 0;
        sum += v[j];
    }
    sdata[tid] = sum;
    __syncthreads();
    for (int off = 1; off < 256; off <<= 1) {
        int t = (tid >= off) ? sdata[tid - off] : 0;
        __syncthreads();
        sdata[tid] += t;
        __syncthreads();
    }
    int excl = sdata[tid] - sum;
    if (tid == 255) partials[blockIdx.x] = sdata[255];
    int run = excl;
#pragma unroll
    for (int j = 0; j < 4; ++j) {
        int idx = base + tid * 4 + j;
        if (idx < n) exc[idx] = run;
        run += v[j];
    }
}

__global__ void scan_partials_kernel(int* __restrict__ partials, int nb)
{
    __shared__ int s[256];
    const int tid = threadIdx.x;
    s[tid] = (tid < nb) ? partials[tid] : 0;
    __syncthreads();
    if (tid == 0) {
        int run = 0;
        for (int i = 0; i < nb; ++i) { int t = s[i]; s[i] = run; run += t; }
    }
    __syncthreads();
    if (tid < nb) partials[tid] = s[tid];
}

__global__ void scan_add_kernel(int* __restrict__ rowptr, const int* __restrict__ partials,
                                int n, int e_total)
{
    int i = blockIdx.x * 256 + threadIdx.x;
    if (i < n) rowptr[i] += partials[i >> 10];
    if (i == 0) rowptr[n] = e_total;
}

__global__ void csr_fill_kernel(const int* __restrict__ row, const int* __restrict__ colv,
                                const float* __restrict__ ea, const float* __restrict__ deg,
                                const int* __restrict__ rowptr, int* __restrict__ cursor,
                                int* __restrict__ ccol, float* __restrict__ cval, int E)
{
    int e = blockIdx.x * 256 + threadIdx.x;
    if (e < E) {
        int r = row[e];
        int p = atomicAdd(&cursor[r], 1);
        int idx = rowptr[r] + p;
        ccol[idx] = colv[e];
        float d = deg[r];
        cval[idx] = ea[e] * (d > 0.f ? 1.f / d : 0.f);
    }
}

// C[M,COLS] = A[M,128] @ W[128,COLS]; 64 rows/block, K tiled by 64, 256 thr.
template<int COLS>
__launch_bounds__(256)
__global__ void gemm_kernel(const float* __restrict__ A, const float* __restrict__ W,
                            float* __restrict__ C, int M)
{
    constexpr int K = 128;
    constexpr int KT = 64;
    constexpr int ROWS = 64;
    constexpr int NCG = COLS / 8;            // threads across cols (8 cols each)
    constexpr int RPT = (ROWS * NCG) / 256;  // rows per thread: 4 (128) / 2 (64)
    __shared__ float Wlds[KT * COLS];        // 32 KB (128) / 16 KB (64)
    __shared__ float Alds[ROWS * (KT + 1)];  // +1 pad -> (r+k)%32 banks, conflict-free

    const int tid = threadIdx.x;
    const int row0 = blockIdx.x * ROWS;
    const int tx = tid % NCG;
    const int ty = tid / NCG;
    const int c0 = tx * 8;
    const int r0 = ty * RPT;

    float acc[RPT][8];
#pragma unroll
    for (int i = 0; i < RPT; ++i)
#pragma unroll
        for (int j = 0; j < 8; ++j) acc[i][j] = 0.f;

    for (int kt = 0; kt < K; kt += KT) {
        const float4* Wg = (const float4*)(W + (size_t)kt * COLS);
        for (int i = tid; i < KT * COLS / 4; i += 256)
            ((float4*)Wlds)[i] = Wg[i];
        for (int i = tid; i < ROWS * (KT / 4); i += 256) {
            int r = i / (KT / 4);
            int kq = i % (KT / 4);
            float4 v = make_float4(0.f, 0.f, 0.f, 0.f);
            int gr = row0 + r;
            if (gr < M) v = *(const float4*)(A + (size_t)gr * K + kt + kq * 4);
            float* dst = &Alds[r * (KT + 1) + kq * 4];
            dst[0] = v.x; dst[1] = v.y; dst[2] = v.z; dst[3] = v.w;
        }
        __syncthreads();
#pragma unroll 8
        for (int kk = 0; kk < KT; ++kk) {
            float4 w0 = *(const float4*)&Wlds[kk * COLS + c0];
            float4 w1 = *(const float4*)&Wlds[kk * COLS + c0 + 4];
#pragma unroll
            for (int i = 0; i < RPT; ++i) {
                float a = Alds[(r0 + i) * (KT + 1) + kk];
                acc[i][0] = fmaf(a, w0.x, acc[i][0]);
                acc[i][1] = fmaf(a, w0.y, acc[i][1]);
                acc[i][2] = fmaf(a, w0.z, acc[i][2]);
                acc[i][3] = fmaf(a, w0.w, acc[i][3]);
                acc[i][4] = fmaf(a, w1.x, acc[i][4]);
                acc[i][5] = fmaf(a, w1.y, acc[i][5]);
                acc[i][6] = fmaf(a, w1.z, acc[i][6]);
                acc[i][7] = fmaf(a, w1.w, acc[i][7]);
            }
        }
        __syncthreads();
    }
#pragma unroll
    for (int i = 0; i < RPT; ++i) {
        int gr = row0 + r0 + i;
        if (gr < M) {
            float4 o0 = make_float4(acc[i][0], acc[i][1], acc[i][2], acc[i][3]);
            float4 o1 = make_float4(acc[i][4], acc[i][5], acc[i][6], acc[i][7]);
            *(float4*)(C + (size_t)gr * COLS + c0) = o0;
            *(float4*)(C + (size_t)gr * COLS + c0 + 4) = o1;
        }
    }
}

// one wave per row, lane = feature (float2/lane for F=128)
// ACT: 0 none, 1 bias+relu, 2 bias+sigmoid, 3 sigmoid
template<int F, int ACT>
__launch_bounds__(256)
__global__ void spmm_kernel(const int* __restrict__ rowptr, const int* __restrict__ ccol,
                            const float* __restrict__ cval, const float* __restrict__ src,
                            const float* __restrict__ bias, float* __restrict__ out, int n)
{
    const int row = blockIdx.x * 4 + (threadIdx.x >> 6);
    const int lane = threadIdx.x & 63;
    if (row >= n) return;
    const int s = rowptr[row];
    const int e = rowptr[row + 1];
    if (F == 64) {
        float acc = 0.f;
        for (int i = s; i < e; ++i) {
            int c = ccol[i];
            float v = cval[i];
            acc = fmaf(v, src[(size_t)c * 64 + lane], acc);
        }
        float x = acc;
        if (ACT == 1) x = fmaxf(x + bias[lane], 0.f);
        else if (ACT == 2) { x += bias[lane]; x = 1.f / (1.f + __expf(-x)); }
        else if (ACT == 3) { x = 1.f / (1.f + __expf(-x)); }
        out[(size_t)row * 64 + lane] = x;
    } else {
        float2 acc = make_float2(0.f, 0.f);
        for (int i = s; i < e; ++i) {
            int c = ccol[i];
            float v = cval[i];
            float2 sv = *(const float2*)(src + (size_t)c * 128 + lane * 2);
            acc.x = fmaf(v, sv.x, acc.x);
            acc.y = fmaf(v, sv.y, acc.y);
        }
        float2 x = acc;
        if (ACT == 1) {
            float2 b = *(const float2*)(bias + lane * 2);
            x.x = fmaxf(x.x + b.x, 0.f);
            x.y = fmaxf(x.y + b.y, 0.f);
        }
        *(float2*)(out + (size_t)row * 128 + lane * 2) = x;
    }
}

extern "C" void kernel_launch(void* const* d_in, const int* in_sizes, int n_in,
                              void* d_out, int out_size, void* d_ws, size_t ws_size,
                              hipStream_t stream)
{
    const float* x    = (const float*)d_in[0];
    const float* soft = (const float*)d_in[1];
    const float* ea   = (const float*)d_in[2];
    const float* w1   = (const float*)d_in[3];
    const float* b1   = (const float*)d_in[4];
    const float* w2   = (const float*)d_in[5];
    const float* b2   = (const float*)d_in[6];
    const int*   eidx = (const int*)d_in[7];

    const int N = in_sizes[0] / 128;
    const int E = in_sizes[2];
    const int* row  = eidx;
    const int* colv = eidx + E;

    uint8_t* ws = (uint8_t*)d_ws;
    size_t off = 0;
    auto alloc = [&](size_t bytes) -> void* {
        void* p = ws + off;
        off += WS_ALIGN(bytes);
        return p;
    };
    float* deg      = (float*)alloc((size_t)N * 4);
    int*   cnt      = (int*)  alloc((size_t)N * 4);
    int*   cursor   = (int*)  alloc((size_t)N * 4);
    int*   rowptr   = (int*)  alloc(((size_t)N + 1) * 4);
    int*   partials = (int*)  alloc(256 * 4);
    int*   ccol     = (int*)  alloc((size_t)E * 4);
    float* cval     = (float*)alloc((size_t)E * 4);
    float* bufA     = (float*)alloc((size_t)N * 128 * 4);  // xw1, then hw2
    float* bufB     = (float*)alloc((size_t)N * 128 * 4);  // h, then label ping-pong

    float* out0 = (float*)d_out;                // x_out [N,64]
    float* out1 = out0 + (size_t)N * 64;        // labels [N,64]
    float* labA = bufB;
    float* labB = bufB + (size_t)N * 64;

    // zero deg/cnt/cursor (contiguous in ws)
    hipMemsetAsync(deg, 0, (size_t)((uint8_t*)rowptr - (uint8_t*)deg), stream);

    const int gE = (E + 255) / 256;
    deg_count_kernel<<<gE, 256, 0, stream>>>(row, ea, deg, cnt, E);

    const int nb = (N + 1023) / 1024;
    scan_block_kernel<<<nb, 256, 0, stream>>>(cnt, rowptr, partials, N);
    scan_partials_kernel<<<1, 256, 0, stream>>>(partials, nb);
    scan_add_kernel<<<(N + 255) / 256, 256, 0, stream>>>(rowptr, partials, N, E);

    csr_fill_kernel<<<gE, 256, 0, stream>>>(row, colv, ea, deg, rowptr, cursor, ccol, cval, E);

    const int gGemm = (N + 63) / 64;
    const int gSp   = (N + 3) / 4;

    gemm_kernel<128><<<gGemm, 256, 0, stream>>>(x, w1, bufA, N);                         // xw1
    spmm_kernel<128, 1><<<gSp, 256, 0, stream>>>(rowptr, ccol, cval, bufA, b1, bufB, N); // h
    gemm_kernel<64><<<gGemm, 256, 0, stream>>>(bufB, w2, bufA, N);                       // hw2
    spmm_kernel<64, 2><<<gSp, 256, 0, stream>>>(rowptr, ccol, cval, bufA, b2, out0, N);  // x_out

    spmm_kernel<64, 0><<<gSp, 256, 0, stream>>>(rowptr, ccol, cval, soft, nullptr, labA, N);
    spmm_kernel<64, 0><<<gSp, 256, 0, stream>>>(rowptr, ccol, cval, labA, nullptr, labB, N);
    spmm_kernel<64, 0><<<gSp, 256, 0, stream>>>(rowptr, ccol, cval, labB, nullptr, labA, N);
    spmm_kernel<64, 0><<<gSp, 256, 0, stream>>>(rowptr, ccol, cval, labA, nullptr, labB, N);
    spmm_kernel<64, 3><<<gSp, 256, 0, stream>>>(rowptr, ccol, cval, labB, nullptr, out1, N);
}

// Round 2
// 513.973 us; speedup vs baseline: 1.5769x; 1.5769x over previous
//
#include <hip/hip_runtime.h>
#include <cstdint>
#include <cstddef>

// ---------------------------------------------------------------------------
// GCN+LPA on MI355X.
// R2: the 6 F=64 spmms were fabric-latency-bound gathers (207 MB/dispatch,
// VALUBusy 14%). Fixes: (a) bf16 intermediates halve gather bytes and let the
// 6.4MB label matrix mostly fit per-XCD L2; (b) 4-edge unrolled gather loop ->
// 4 loads in flight/wave; (c) packed int2 (col,val) edge records.
// All accumulation stays f32; only storage of xw1/logits/labels is bf16.
// ---------------------------------------------------------------------------

#define WS_ALIGN(x) (((x) + 255) & ~((size_t)255))

__device__ __forceinline__ unsigned short f2bf(float f) {
    unsigned u = __float_as_uint(f);
    u += 0x7fffu + ((u >> 16) & 1u);          // round-to-nearest-even
    return (unsigned short)(u >> 16);
}
__device__ __forceinline__ float bf2f(unsigned short h) {
    return __uint_as_float(((unsigned)h) << 16);
}
__device__ __forceinline__ float sigmoidf(float x) {
    return 1.f / (1.f + __expf(-x));
}

// ---------------------------------------------------------------------------
// CSR build
// ---------------------------------------------------------------------------
__global__ void deg_count_kernel(const int* __restrict__ row, const float* __restrict__ ea,
                                 float* __restrict__ deg, int* __restrict__ cnt, int E)
{
    int e = blockIdx.x * 256 + threadIdx.x;
    if (e < E) {
        int r = row[e];
        atomicAdd(&deg[r], ea[e]);
        atomicAdd(&cnt[r], 1);
    }
}

__global__ void scan_block_kernel(const int* __restrict__ cnt, int* __restrict__ exc,
                                  int* __restrict__ partials, int n)
{
    __shared__ int sdata[256];
    const int tid = threadIdx.x;
    const int base = blockIdx.x * 1024;
    int v[4];
    int sum = 0;
#pragma unroll
    for (int j = 0; j < 4; ++j) {
        int idx = base + tid * 4 + j;
        v[j] = (idx < n) ? cnt[idx] : 0;
        sum += v[j];
    }
    sdata[tid] = sum;
    __syncthreads();
    for (int off = 1; off < 256; off <<= 1) {
        int t = (tid >= off) ? sdata[tid - off] : 0;
        __syncthreads();
        sdata[tid] += t;
        __syncthreads();
    }
    int excl = sdata[tid] - sum;
    if (tid == 255) partials[blockIdx.x] = sdata[255];
    int run = excl;
#pragma unroll
    for (int j = 0; j < 4; ++j) {
        int idx = base + tid * 4 + j;
        if (idx < n) exc[idx] = run;
        run += v[j];
    }
}

__global__ void scan_partials_kernel(int* __restrict__ partials, int nb)
{
    __shared__ int s[256];
    const int tid = threadIdx.x;
    s[tid] = (tid < nb) ? partials[tid] : 0;
    __syncthreads();
    if (tid == 0) {
        int run = 0;
        for (int i = 0; i < nb; ++i) { int t = s[i]; s[i] = run; run += t; }
    }
    __syncthreads();
    if (tid < nb) partials[tid] = s[tid];
}

__global__ void scan_add_kernel(int* __restrict__ rowptr, const int* __restrict__ partials,
                                int n, int e_total)
{
    int i = blockIdx.x * 256 + threadIdx.x;
    if (i < n) rowptr[i] += partials[i >> 10];
    if (i == 0) rowptr[n] = e_total;
}

__global__ void csr_fill_kernel(const int* __restrict__ row, const int* __restrict__ colv,
                                const float* __restrict__ ea, const float* __restrict__ deg,
                                const int* __restrict__ rowptr, int* __restrict__ cursor,
                                int2* __restrict__ edges, int E)
{
    int e = blockIdx.x * 256 + threadIdx.x;
    if (e < E) {
        int r = row[e];
        int p = atomicAdd(&cursor[r], 1);
        int idx = rowptr[r] + p;
        float d = deg[r];
        float w = ea[e] * (d > 0.f ? 1.f / d : 0.f);
        edges[idx] = make_int2(colv[e], __float_as_int(w));
    }
}

__global__ void f32_to_bf16_kernel(const float* __restrict__ in, unsigned short* __restrict__ out,
                                   int n2)  // n2 = n/2 pairs
{
    int i = blockIdx.x * 256 + threadIdx.x;
    if (i < n2) {
        float2 v = ((const float2*)in)[i];
        unsigned p = (unsigned)f2bf(v.x) | ((unsigned)f2bf(v.y) << 16);
        ((unsigned*)out)[i] = p;
    }
}

// ---------------------------------------------------------------------------
// GEMM: C_bf16[M,COLS] = A_f32[M,128] @ W_f32[128,COLS]; 64 rows/block.
// ---------------------------------------------------------------------------
template<int COLS>
__launch_bounds__(256)
__global__ void gemm_kernel(const float* __restrict__ A, const float* __restrict__ W,
                            unsigned short* __restrict__ C, int M)
{
    constexpr int K = 128;
    constexpr int KT = 64;
    constexpr int ROWS = 64;
    constexpr int NCG = COLS / 8;
    constexpr int RPT = (ROWS * NCG) / 256;
    __shared__ float Wlds[KT * COLS];
    __shared__ float Alds[ROWS * (KT + 1)];

    const int tid = threadIdx.x;
    const int row0 = blockIdx.x * ROWS;
    const int tx = tid % NCG;
    const int ty = tid / NCG;
    const int c0 = tx * 8;
    const int r0 = ty * RPT;

    float acc[RPT][8];
#pragma unroll
    for (int i = 0; i < RPT; ++i)
#pragma unroll
        for (int j = 0; j < 8; ++j) acc[i][j] = 0.f;

    for (int kt = 0; kt < K; kt += KT) {
        const float4* Wg = (const float4*)(W + (size_t)kt * COLS);
        for (int i = tid; i < KT * COLS / 4; i += 256)
            ((float4*)Wlds)[i] = Wg[i];
        for (int i = tid; i < ROWS * (KT / 4); i += 256) {
            int r = i / (KT / 4);
            int kq = i % (KT / 4);
            float4 v = make_float4(0.f, 0.f, 0.f, 0.f);
            int gr = row0 + r;
            if (gr < M) v = *(const float4*)(A + (size_t)gr * K + kt + kq * 4);
            float* dst = &Alds[r * (KT + 1) + kq * 4];
            dst[0] = v.x; dst[1] = v.y; dst[2] = v.z; dst[3] = v.w;
        }
        __syncthreads();
#pragma unroll 8
        for (int kk = 0; kk < KT; ++kk) {
            float4 w0 = *(const float4*)&Wlds[kk * COLS + c0];
            float4 w1 = *(const float4*)&Wlds[kk * COLS + c0 + 4];
#pragma unroll
            for (int i = 0; i < RPT; ++i) {
                float a = Alds[(r0 + i) * (KT + 1) + kk];
                acc[i][0] = fmaf(a, w0.x, acc[i][0]);
                acc[i][1] = fmaf(a, w0.y, acc[i][1]);
                acc[i][2] = fmaf(a, w0.z, acc[i][2]);
                acc[i][3] = fmaf(a, w0.w, acc[i][3]);
                acc[i][4] = fmaf(a, w1.x, acc[i][4]);
                acc[i][5] = fmaf(a, w1.y, acc[i][5]);
                acc[i][6] = fmaf(a, w1.z, acc[i][6]);
                acc[i][7] = fmaf(a, w1.w, acc[i][7]);
            }
        }
        __syncthreads();
    }
#pragma unroll
    for (int i = 0; i < RPT; ++i) {
        int gr = row0 + r0 + i;
        if (gr < M) {
            uint4 o;
            o.x = (unsigned)f2bf(acc[i][0]) | ((unsigned)f2bf(acc[i][1]) << 16);
            o.y = (unsigned)f2bf(acc[i][2]) | ((unsigned)f2bf(acc[i][3]) << 16);
            o.z = (unsigned)f2bf(acc[i][4]) | ((unsigned)f2bf(acc[i][5]) << 16);
            o.w = (unsigned)f2bf(acc[i][6]) | ((unsigned)f2bf(acc[i][7]) << 16);
            *(uint4*)(C + (size_t)gr * COLS + c0) = o;
        }
    }
}

// ---------------------------------------------------------------------------
// SpMM F=128, bf16 src, f32 out, bias+relu. One wave/row, lane = 2 feats.
// ---------------------------------------------------------------------------
__launch_bounds__(256)
__global__ void spmm128_relu(const int* __restrict__ rowptr, const int2* __restrict__ edges,
                             const unsigned short* __restrict__ src,
                             const float* __restrict__ bias, float* __restrict__ out, int n)
{
    const int row = blockIdx.x * 4 + (threadIdx.x >> 6);
    const int lane = threadIdx.x & 63;
    if (row >= n) return;
    const int s = rowptr[row];
    const int e = rowptr[row + 1];
    const unsigned* us = (const unsigned*)src;   // 64 uints / row

    float a0x = 0.f, a0y = 0.f, a1x = 0.f, a1y = 0.f;
    float a2x = 0.f, a2y = 0.f, a3x = 0.f, a3y = 0.f;
    int i = s;
    for (; i + 4 <= e; i += 4) {
        int2 e0 = edges[i], e1 = edges[i + 1], e2 = edges[i + 2], e3 = edges[i + 3];
        unsigned u0 = us[(size_t)e0.x * 64 + lane];
        unsigned u1 = us[(size_t)e1.x * 64 + lane];
        unsigned u2 = us[(size_t)e2.x * 64 + lane];
        unsigned u3 = us[(size_t)e3.x * 64 + lane];
        float w0 = __int_as_float(e0.y), w1 = __int_as_float(e1.y);
        float w2 = __int_as_float(e2.y), w3 = __int_as_float(e3.y);
        a0x = fmaf(w0, __uint_as_float(u0 << 16), a0x);
        a0y = fmaf(w0, __uint_as_float(u0 & 0xffff0000u), a0y);
        a1x = fmaf(w1, __uint_as_float(u1 << 16), a1x);
        a1y = fmaf(w1, __uint_as_float(u1 & 0xffff0000u), a1y);
        a2x = fmaf(w2, __uint_as_float(u2 << 16), a2x);
        a2y = fmaf(w2, __uint_as_float(u2 & 0xffff0000u), a2y);
        a3x = fmaf(w3, __uint_as_float(u3 << 16), a3x);
        a3y = fmaf(w3, __uint_as_float(u3 & 0xffff0000u), a3y);
    }
    for (; i < e; ++i) {
        int2 e0 = edges[i];
        unsigned u0 = us[(size_t)e0.x * 64 + lane];
        float w0 = __int_as_float(e0.y);
        a0x = fmaf(w0, __uint_as_float(u0 << 16), a0x);
        a0y = fmaf(w0, __uint_as_float(u0 & 0xffff0000u), a0y);
    }
    float vx = (a0x + a1x) + (a2x + a3x);
    float vy = (a0y + a1y) + (a2y + a3y);
    float2 b = *(const float2*)(bias + lane * 2);
    vx = fmaxf(vx + b.x, 0.f);
    vy = fmaxf(vy + b.y, 0.f);
    *(float2*)(out + (size_t)row * 128 + lane * 2) = make_float2(vx, vy);
}

// ---------------------------------------------------------------------------
// SpMM F=64, bf16 src. ACT: 0 none, 2 bias+sigmoid, 3 sigmoid.
// OUT_BF16: store bf16 (LPA intermediates) else f32.
// ---------------------------------------------------------------------------
template<int ACT, bool OUT_BF16>
__launch_bounds__(256)
__global__ void spmm64_kernel(const int* __restrict__ rowptr, const int2* __restrict__ edges,
                              const unsigned short* __restrict__ src,
                              const float* __restrict__ bias, void* __restrict__ out, int n)
{
    const int row = blockIdx.x * 4 + (threadIdx.x >> 6);
    const int lane = threadIdx.x & 63;
    if (row >= n) return;
    const int s = rowptr[row];
    const int e = rowptr[row + 1];

    float a0 = 0.f, a1 = 0.f, a2 = 0.f, a3 = 0.f;
    int i = s;
    for (; i + 4 <= e; i += 4) {
        int2 e0 = edges[i], e1 = edges[i + 1], e2 = edges[i + 2], e3 = edges[i + 3];
        float s0 = bf2f(src[(size_t)e0.x * 64 + lane]);
        float s1 = bf2f(src[(size_t)e1.x * 64 + lane]);
        float s2 = bf2f(src[(size_t)e2.x * 64 + lane]);
        float s3 = bf2f(src[(size_t)e3.x * 64 + lane]);
        a0 = fmaf(__int_as_float(e0.y), s0, a0);
        a1 = fmaf(__int_as_float(e1.y), s1, a1);
        a2 = fmaf(__int_as_float(e2.y), s2, a2);
        a3 = fmaf(__int_as_float(e3.y), s3, a3);
    }
    for (; i < e; ++i) {
        int2 e0 = edges[i];
        a0 = fmaf(__int_as_float(e0.y), bf2f(src[(size_t)e0.x * 64 + lane]), a0);
    }
    float v = (a0 + a1) + (a2 + a3);
    if (ACT == 2) v = sigmoidf(v + bias[lane]);
    else if (ACT == 3) v = sigmoidf(v);
    if (OUT_BF16)
        ((unsigned short*)out)[(size_t)row * 64 + lane] = f2bf(v);
    else
        ((float*)out)[(size_t)row * 64 + lane] = v;
}

// ---------------------------------------------------------------------------
extern "C" void kernel_launch(void* const* d_in, const int* in_sizes, int n_in,
                              void* d_out, int out_size, void* d_ws, size_t ws_size,
                              hipStream_t stream)
{
    const float* x    = (const float*)d_in[0];
    const float* soft = (const float*)d_in[1];
    const float* ea   = (const float*)d_in[2];
    const float* w1   = (const float*)d_in[3];
    const float* b1   = (const float*)d_in[4];
    const float* w2   = (const float*)d_in[5];
    const float* b2   = (const float*)d_in[6];
    const int*   eidx = (const int*)d_in[7];

    const int N = in_sizes[0] / 128;
    const int E = in_sizes[2];
    const int* row  = eidx;
    const int* colv = eidx + E;

    uint8_t* ws = (uint8_t*)d_ws;
    size_t off = 0;
    auto alloc = [&](size_t bytes) -> void* {
        void* p = ws + off;
        off += WS_ALIGN(bytes);
        return p;
    };
    float* deg      = (float*)alloc((size_t)N * 4);
    int*   cnt      = (int*)  alloc((size_t)N * 4);
    int*   cursor   = (int*)  alloc((size_t)N * 4);
    int*   rowptr   = (int*)  alloc(((size_t)N + 1) * 4);
    int*   partials = (int*)  alloc(256 * 4);
    int2*  edges    = (int2*) alloc((size_t)E * 8);
    unsigned short* xw1b    = (unsigned short*)alloc((size_t)N * 128 * 2);
    float*          h       = (float*)         alloc((size_t)N * 128 * 4);
    unsigned short* logitsb = (unsigned short*)alloc((size_t)N * 64 * 2);
    unsigned short* softb   = (unsigned short*)alloc((size_t)N * 64 * 2);
    unsigned short* labA    = (unsigned short*)alloc((size_t)N * 64 * 2);
    unsigned short* labB    = (unsigned short*)alloc((size_t)N * 64 * 2);

    float* out0 = (float*)d_out;             // x_out [N,64]
    float* out1 = out0 + (size_t)N * 64;     // labels [N,64]

    hipMemsetAsync(deg, 0, (size_t)((uint8_t*)rowptr - (uint8_t*)deg), stream);

    const int gE = (E + 255) / 256;
    deg_count_kernel<<<gE, 256, 0, stream>>>(row, ea, deg, cnt, E);

    const int nb = (N + 1023) / 1024;
    scan_block_kernel<<<nb, 256, 0, stream>>>(cnt, rowptr, partials, N);
    scan_partials_kernel<<<1, 256, 0, stream>>>(partials, nb);
    scan_add_kernel<<<(N + 255) / 256, 256, 0, stream>>>(rowptr, partials, N, E);
    csr_fill_kernel<<<gE, 256, 0, stream>>>(row, colv, ea, deg, rowptr, cursor, edges, E);

    // soft_labels -> bf16
    const int n2 = (N * 64) / 2;
    f32_to_bf16_kernel<<<(n2 + 255) / 256, 256, 0, stream>>>(soft, softb, n2);

    const int gGemm = (N + 63) / 64;
    const int gSp   = (N + 3) / 4;

    gemm_kernel<128><<<gGemm, 256, 0, stream>>>(x, w1, xw1b, N);                  // xw1 (bf16)
    spmm128_relu<<<gSp, 256, 0, stream>>>(rowptr, edges, xw1b, b1, h, N);         // h (f32)
    gemm_kernel<64><<<gGemm, 256, 0, stream>>>(h, w2, logitsb, N);                // logits (bf16)
    spmm64_kernel<2, false><<<gSp, 256, 0, stream>>>(rowptr, edges, logitsb, b2, out0, N);

    spmm64_kernel<0, true ><<<gSp, 256, 0, stream>>>(rowptr, edges, softb, nullptr, labA, N);
    spmm64_kernel<0, true ><<<gSp, 256, 0, stream>>>(rowptr, edges, labA, nullptr, labB, N);
    spmm64_kernel<0, true ><<<gSp, 256, 0, stream>>>(rowptr, edges, labB, nullptr, labA, N);
    spmm64_kernel<0, true ><<<gSp, 256, 0, stream>>>(rowptr, edges, labA, nullptr, labB, N);
    spmm64_kernel<3, false><<<gSp, 256, 0, stream>>>(rowptr, edges, labB, nullptr, out1, N);
}

// Round 3
// 399.235 us; speedup vs baseline: 2.0301x; 1.2874x over previous
//
#include <hip/hip_runtime.h>
#include <cstdint>
#include <cstddef>

// ---------------------------------------------------------------------------
// GCN+LPA on MI355X.
// R3: R2 showed deg_count at 76us with VALUBusy 0.26% and WRITE_SIZE = 50MB =
// 1.6M atomics x 32B write-through: global scattered atomics serialize at the
// coherence point (~21 Gops/s). csr_fill pays the same. Replace the whole CSR
// build with a 2-level counting sort: LDS histograms + one global atomic per
// (block,bucket) (50k total), then per-bucket finalize with LDS-only atomics.
// Also 8-deep unrolled gather loops in the spmms (VGPR=12 -> huge ILP room).
// NOTE: packing assumes N < 65536 (row/col fit 16 bits). N = 50000 here.
// ---------------------------------------------------------------------------

#define WS_ALIGN(x) (((x) + 255) & ~((size_t)255))

__device__ __forceinline__ unsigned short f2bf(float f) {
    unsigned u = __float_as_uint(f);
    u += 0x7fffu + ((u >> 16) & 1u);          // round-to-nearest-even
    return (unsigned short)(u >> 16);
}
__device__ __forceinline__ float bf2f(unsigned short h) {
    return __uint_as_float(((unsigned)h) << 16);
}
__device__ __forceinline__ float sigmoidf(float x) {
    return 1.f / (1.f + __expf(-x));
}

static const int NBLK = 256;   // blocks for binning passes
#define MAXNB 256              // max coarse buckets supported (N <= 65536)

// ---------------------------------------------------------------------------
// Pass A1: per-block LDS histogram of row>>8; one global atomic per (blk,bin).
// ---------------------------------------------------------------------------
__launch_bounds__(256)
__global__ void binA_count(const int* __restrict__ row, int* __restrict__ bucket_count,
                           int* __restrict__ bases, int E, int chunk, int NB)
{
    __shared__ int hist[MAXNB];
    const int t = threadIdx.x;
    const int blk = blockIdx.x;
    if (t < NB) hist[t] = 0;
    __syncthreads();
    const int s = blk * chunk;
    const int e = min(E, s + chunk);
    for (int i = s + t; i < e; i += 256)
        atomicAdd(&hist[row[i] >> 8], 1);
    __syncthreads();
    if (t < NB)
        bases[blk * NB + t] = atomicAdd(&bucket_count[t], hist[t]);
}

// Pass A2: exclusive scan of bucket_count -> bucket_start[0..NB]
__launch_bounds__(256)
__global__ void bin_scan(const int* __restrict__ bucket_count, int* __restrict__ bucket_start,
                         int NB)
{
    __shared__ int s[256];
    const int t = threadIdx.x;
    int v = (t < NB) ? bucket_count[t] : 0;
    s[t] = v;
    __syncthreads();
    for (int off = 1; off < 256; off <<= 1) {
        int u = (t >= off) ? s[t - off] : 0;
        __syncthreads();
        s[t] += u;
        __syncthreads();
    }
    int excl = s[t] - v;
    if (t <= NB) bucket_start[t] = excl;   // t==NB: total == E
}

// Pass A3: scatter (rowLocal<<16 | col, ea) into coarse bucket regions.
__launch_bounds__(256)
__global__ void binA_scatter(const int* __restrict__ row, const int* __restrict__ colv,
                             const float* __restrict__ ea,
                             const int* __restrict__ bucket_start, const int* __restrict__ bases,
                             int2* __restrict__ bk, int E, int chunk, int NB)
{
    __shared__ int cur[MAXNB];
    const int t = threadIdx.x;
    const int blk = blockIdx.x;
    if (t < NB) cur[t] = bucket_start[t] + bases[blk * NB + t];
    __syncthreads();
    const int s = blk * chunk;
    const int e = min(E, s + chunk);
    for (int i = s + t; i < e; i += 256) {
        int r = row[i];
        int bin = r >> 8;
        int pos = atomicAdd(&cur[bin], 1);
        bk[pos] = make_int2(((r & 255) << 16) | colv[i], __float_as_int(ea[i]));
    }
}

// Pass B: per-bucket (256 rows) finalize: LDS count/deg/scan -> rowptr + edges.
__launch_bounds__(256)
__global__ void binB(const int2* __restrict__ bk, const int* __restrict__ bucket_start,
                     int* __restrict__ rowptr, int2* __restrict__ edges, int N)
{
    __shared__ int cnt[256];
    __shared__ float deg[256];
    __shared__ float inv[256];
    __shared__ int excl_s[256];
    __shared__ int cur[256];
    __shared__ int scantmp[256];
    const int b = blockIdx.x;
    const int t = threadIdx.x;
    const int s = bucket_start[b];
    const int e = bucket_start[b + 1];
    cnt[t] = 0;
    deg[t] = 0.f;
    __syncthreads();
    for (int i = s + t; i < e; i += 256) {
        int2 v = bk[i];
        int rl = ((unsigned)v.x) >> 16;
        atomicAdd(&cnt[rl], 1);
        atomicAdd(&deg[rl], __int_as_float(v.y));
    }
    __syncthreads();
    const int myc = cnt[t];
    scantmp[t] = myc;
    __syncthreads();
    for (int off = 1; off < 256; off <<= 1) {
        int u = (t >= off) ? scantmp[t - off] : 0;
        __syncthreads();
        scantmp[t] += u;
        __syncthreads();
    }
    const int excl = scantmp[t] - myc;
    excl_s[t] = excl;
    float d = deg[t];
    inv[t] = (d > 0.f) ? 1.f / d : 0.f;
    cur[t] = 0;
    const int gr = b * 256 + t;
    if (gr <= N) rowptr[gr] = s + excl;
    __syncthreads();
    for (int i = s + t; i < e; i += 256) {
        int2 v = bk[i];
        int rl = ((unsigned)v.x) >> 16;
        int c = v.x & 0xffff;
        int p = s + excl_s[rl] + atomicAdd(&cur[rl], 1);
        edges[p] = make_int2(c, __float_as_int(__int_as_float(v.y) * inv[rl]));
    }
}

__global__ void f32_to_bf16_kernel(const float* __restrict__ in, unsigned short* __restrict__ out,
                                   int n2)  // n2 = n/2 pairs
{
    int i = blockIdx.x * 256 + threadIdx.x;
    if (i < n2) {
        float2 v = ((const float2*)in)[i];
        unsigned p = (unsigned)f2bf(v.x) | ((unsigned)f2bf(v.y) << 16);
        ((unsigned*)out)[i] = p;
    }
}

// ---------------------------------------------------------------------------
// GEMM: C_bf16[M,COLS] = A_f32[M,128] @ W_f32[128,COLS]; 64 rows/block.
// ---------------------------------------------------------------------------
template<int COLS>
__launch_bounds__(256)
__global__ void gemm_kernel(const float* __restrict__ A, const float* __restrict__ W,
                            unsigned short* __restrict__ C, int M)
{
    constexpr int K = 128;
    constexpr int KT = 64;
    constexpr int ROWS = 64;
    constexpr int NCG = COLS / 8;
    constexpr int RPT = (ROWS * NCG) / 256;
    __shared__ float Wlds[KT * COLS];
    __shared__ float Alds[ROWS * (KT + 1)];

    const int tid = threadIdx.x;
    const int row0 = blockIdx.x * ROWS;
    const int tx = tid % NCG;
    const int ty = tid / NCG;
    const int c0 = tx * 8;
    const int r0 = ty * RPT;

    float acc[RPT][8];
#pragma unroll
    for (int i = 0; i < RPT; ++i)
#pragma unroll
        for (int j = 0; j < 8; ++j) acc[i][j] = 0.f;

    for (int kt = 0; kt < K; kt += KT) {
        const float4* Wg = (const float4*)(W + (size_t)kt * COLS);
        for (int i = tid; i < KT * COLS / 4; i += 256)
            ((float4*)Wlds)[i] = Wg[i];
        for (int i = tid; i < ROWS * (KT / 4); i += 256) {
            int r = i / (KT / 4);
            int kq = i % (KT / 4);
            float4 v = make_float4(0.f, 0.f, 0.f, 0.f);
            int gr = row0 + r;
            if (gr < M) v = *(const float4*)(A + (size_t)gr * K + kt + kq * 4);
            float* dst = &Alds[r * (KT + 1) + kq * 4];
            dst[0] = v.x; dst[1] = v.y; dst[2] = v.z; dst[3] = v.w;
        }
        __syncthreads();
#pragma unroll 8
        for (int kk = 0; kk < KT; ++kk) {
            float4 w0 = *(const float4*)&Wlds[kk * COLS + c0];
            float4 w1 = *(const float4*)&Wlds[kk * COLS + c0 + 4];
#pragma unroll
            for (int i = 0; i < RPT; ++i) {
                float a = Alds[(r0 + i) * (KT + 1) + kk];
                acc[i][0] = fmaf(a, w0.x, acc[i][0]);
                acc[i][1] = fmaf(a, w0.y, acc[i][1]);
                acc[i][2] = fmaf(a, w0.z, acc[i][2]);
                acc[i][3] = fmaf(a, w0.w, acc[i][3]);
                acc[i][4] = fmaf(a, w1.x, acc[i][4]);
                acc[i][5] = fmaf(a, w1.y, acc[i][5]);
                acc[i][6] = fmaf(a, w1.z, acc[i][6]);
                acc[i][7] = fmaf(a, w1.w, acc[i][7]);
            }
        }
        __syncthreads();
    }
#pragma unroll
    for (int i = 0; i < RPT; ++i) {
        int gr = row0 + r0 + i;
        if (gr < M) {
            uint4 o;
            o.x = (unsigned)f2bf(acc[i][0]) | ((unsigned)f2bf(acc[i][1]) << 16);
            o.y = (unsigned)f2bf(acc[i][2]) | ((unsigned)f2bf(acc[i][3]) << 16);
            o.z = (unsigned)f2bf(acc[i][4]) | ((unsigned)f2bf(acc[i][5]) << 16);
            o.w = (unsigned)f2bf(acc[i][6]) | ((unsigned)f2bf(acc[i][7]) << 16);
            *(uint4*)(C + (size_t)gr * COLS + c0) = o;
        }
    }
}

// ---------------------------------------------------------------------------
// SpMM F=128, bf16 src, f32 out, bias+relu. One wave/row, lane = 2 feats.
// 8-deep unrolled gather.
// ---------------------------------------------------------------------------
__launch_bounds__(256)
__global__ void spmm128_relu(const int* __restrict__ rowptr, const int2* __restrict__ edges,
                             const unsigned short* __restrict__ src,
                             const float* __restrict__ bias, float* __restrict__ out, int n)
{
    const int row = blockIdx.x * 4 + (threadIdx.x >> 6);
    const int lane = threadIdx.x & 63;
    if (row >= n) return;
    const int s = rowptr[row];
    const int e = rowptr[row + 1];
    const unsigned* us = (const unsigned*)src;   // 64 uints / row

    float ax[8], ay[8];
#pragma unroll
    for (int j = 0; j < 8; ++j) { ax[j] = 0.f; ay[j] = 0.f; }
    int i = s;
    for (; i + 8 <= e; i += 8) {
        int2 ed[8];
        unsigned u[8];
#pragma unroll
        for (int j = 0; j < 8; ++j) ed[j] = edges[i + j];
#pragma unroll
        for (int j = 0; j < 8; ++j) u[j] = us[(size_t)ed[j].x * 64 + lane];
#pragma unroll
        for (int j = 0; j < 8; ++j) {
            float w = __int_as_float(ed[j].y);
            ax[j] = fmaf(w, __uint_as_float(u[j] << 16), ax[j]);
            ay[j] = fmaf(w, __uint_as_float(u[j] & 0xffff0000u), ay[j]);
        }
    }
    for (; i + 4 <= e; i += 4) {
        int2 ed[4];
        unsigned u[4];
#pragma unroll
        for (int j = 0; j < 4; ++j) ed[j] = edges[i + j];
#pragma unroll
        for (int j = 0; j < 4; ++j) u[j] = us[(size_t)ed[j].x * 64 + lane];
#pragma unroll
        for (int j = 0; j < 4; ++j) {
            float w = __int_as_float(ed[j].y);
            ax[j] = fmaf(w, __uint_as_float(u[j] << 16), ax[j]);
            ay[j] = fmaf(w, __uint_as_float(u[j] & 0xffff0000u), ay[j]);
        }
    }
    for (; i < e; ++i) {
        int2 e0 = edges[i];
        unsigned u0 = us[(size_t)e0.x * 64 + lane];
        float w0 = __int_as_float(e0.y);
        ax[0] = fmaf(w0, __uint_as_float(u0 << 16), ax[0]);
        ay[0] = fmaf(w0, __uint_as_float(u0 & 0xffff0000u), ay[0]);
    }
    float vx = ((ax[0] + ax[1]) + (ax[2] + ax[3])) + ((ax[4] + ax[5]) + (ax[6] + ax[7]));
    float vy = ((ay[0] + ay[1]) + (ay[2] + ay[3])) + ((ay[4] + ay[5]) + (ay[6] + ay[7]));
    float2 b = *(const float2*)(bias + lane * 2);
    vx = fmaxf(vx + b.x, 0.f);
    vy = fmaxf(vy + b.y, 0.f);
    *(float2*)(out + (size_t)row * 128 + lane * 2) = make_float2(vx, vy);
}

// ---------------------------------------------------------------------------
// SpMM F=64, bf16 src. ACT: 0 none, 2 bias+sigmoid, 3 sigmoid.
// OUT_BF16: store bf16 (LPA intermediates) else f32. 8-deep unrolled gather.
// ---------------------------------------------------------------------------
template<int ACT, bool OUT_BF16>
__launch_bounds__(256)
__global__ void spmm64_kernel(const int* __restrict__ rowptr, const int2* __restrict__ edges,
                              const unsigned short* __restrict__ src,
                              const float* __restrict__ bias, void* __restrict__ out, int n)
{
    const int row = blockIdx.x * 4 + (threadIdx.x >> 6);
    const int lane = threadIdx.x & 63;
    if (row >= n) return;
    const int s = rowptr[row];
    const int e = rowptr[row + 1];

    float a[8];
#pragma unroll
    for (int j = 0; j < 8; ++j) a[j] = 0.f;
    int i = s;
    for (; i + 8 <= e; i += 8) {
        int2 ed[8];
        float sv[8];
#pragma unroll
        for (int j = 0; j < 8; ++j) ed[j] = edges[i + j];
#pragma unroll
        for (int j = 0; j < 8; ++j) sv[j] = bf2f(src[(size_t)ed[j].x * 64 + lane]);
#pragma unroll
        for (int j = 0; j < 8; ++j) a[j] = fmaf(__int_as_float(ed[j].y), sv[j], a[j]);
    }
    for (; i + 4 <= e; i += 4) {
        int2 ed[4];
        float sv[4];
#pragma unroll
        for (int j = 0; j < 4; ++j) ed[j] = edges[i + j];
#pragma unroll
        for (int j = 0; j < 4; ++j) sv[j] = bf2f(src[(size_t)ed[j].x * 64 + lane]);
#pragma unroll
        for (int j = 0; j < 4; ++j) a[j] = fmaf(__int_as_float(ed[j].y), sv[j], a[j]);
    }
    for (; i < e; ++i) {
        int2 e0 = edges[i];
        a[0] = fmaf(__int_as_float(e0.y), bf2f(src[(size_t)e0.x * 64 + lane]), a[0]);
    }
    float v = ((a[0] + a[1]) + (a[2] + a[3])) + ((a[4] + a[5]) + (a[6] + a[7]));
    if (ACT == 2) v = sigmoidf(v + bias[lane]);
    else if (ACT == 3) v = sigmoidf(v);
    if (OUT_BF16)
        ((unsigned short*)out)[(size_t)row * 64 + lane] = f2bf(v);
    else
        ((float*)out)[(size_t)row * 64 + lane] = v;
}

// ---------------------------------------------------------------------------
extern "C" void kernel_launch(void* const* d_in, const int* in_sizes, int n_in,
                              void* d_out, int out_size, void* d_ws, size_t ws_size,
                              hipStream_t stream)
{
    const float* x    = (const float*)d_in[0];
    const float* soft = (const float*)d_in[1];
    const float* ea   = (const float*)d_in[2];
    const float* w1   = (const float*)d_in[3];
    const float* b1   = (const float*)d_in[4];
    const float* w2   = (const float*)d_in[5];
    const float* b2   = (const float*)d_in[6];
    const int*   eidx = (const int*)d_in[7];

    const int N = in_sizes[0] / 128;
    const int E = in_sizes[2];
    const int* row  = eidx;
    const int* colv = eidx + E;
    const int NB = (N + 255) / 256;            // coarse buckets (<= 256)
    const int chunk = (E + NBLK - 1) / NBLK;

    uint8_t* ws = (uint8_t*)d_ws;
    size_t off = 0;
    auto alloc = [&](size_t bytes) -> void* {
        void* p = ws + off;
        off += WS_ALIGN(bytes);
        return p;
    };
    int*  bucket_count = (int*) alloc((size_t)NB * 4);
    int*  bucket_start = (int*) alloc(((size_t)NB + 1) * 4);
    int*  bases        = (int*) alloc((size_t)NBLK * NB * 4);
    int*  rowptr       = (int*) alloc(((size_t)N + 1) * 4);
    int2* bk           = (int2*)alloc((size_t)E * 8);
    int2* edges        = (int2*)alloc((size_t)E * 8);
    unsigned short* xw1b    = (unsigned short*)alloc((size_t)N * 128 * 2);
    float*          h       = (float*)         alloc((size_t)N * 128 * 4);
    unsigned short* logitsb = (unsigned short*)alloc((size_t)N * 64 * 2);
    unsigned short* softb   = (unsigned short*)alloc((size_t)N * 64 * 2);
    unsigned short* labA    = (unsigned short*)alloc((size_t)N * 64 * 2);
    unsigned short* labB    = (unsigned short*)alloc((size_t)N * 64 * 2);

    float* out0 = (float*)d_out;             // x_out [N,64]
    float* out1 = out0 + (size_t)N * 64;     // labels [N,64]

    hipMemsetAsync(bucket_count, 0, (size_t)NB * 4, stream);

    // CSR build: counting sort, LDS atomics only (+50k block-level globals)
    binA_count<<<NBLK, 256, 0, stream>>>(row, bucket_count, bases, E, chunk, NB);
    bin_scan<<<1, 256, 0, stream>>>(bucket_count, bucket_start, NB);
    binA_scatter<<<NBLK, 256, 0, stream>>>(row, colv, ea, bucket_start, bases, bk, E, chunk, NB);
    binB<<<NB, 256, 0, stream>>>(bk, bucket_start, rowptr, edges, N);

    // soft_labels -> bf16
    const int n2 = (N * 64) / 2;
    f32_to_bf16_kernel<<<(n2 + 255) / 256, 256, 0, stream>>>(soft, softb, n2);

    const int gGemm = (N + 63) / 64;
    const int gSp   = (N + 3) / 4;

    gemm_kernel<128><<<gGemm, 256, 0, stream>>>(x, w1, xw1b, N);                  // xw1 (bf16)
    spmm128_relu<<<gSp, 256, 0, stream>>>(rowptr, edges, xw1b, b1, h, N);         // h (f32)
    gemm_kernel<64><<<gGemm, 256, 0, stream>>>(h, w2, logitsb, N);                // logits (bf16)
    spmm64_kernel<2, false><<<gSp, 256, 0, stream>>>(rowptr, edges, logitsb, b2, out0, N);

    spmm64_kernel<0, true ><<<gSp, 256, 0, stream>>>(rowptr, edges, softb, nullptr, labA, N);
    spmm64_kernel<0, true ><<<gSp, 256, 0, stream>>>(rowptr, edges, labA, nullptr, labB, N);
    spmm64_kernel<0, true ><<<gSp, 256, 0, stream>>>(rowptr, edges, labB, nullptr, labA, N);
    spmm64_kernel<0, true ><<<gSp, 256, 0, stream>>>(rowptr, edges, labA, nullptr, labB, N);
    spmm64_kernel<3, false><<<gSp, 256, 0, stream>>>(rowptr, edges, labB, nullptr, out1, N);
}

// Round 4
// 366.997 us; speedup vs baseline: 2.2084x; 1.0878x over previous
//
#include <hip/hip_runtime.h>
#include <cstdint>
#include <cstddef>

// ---------------------------------------------------------------------------
// GCN+LPA on MI355X.
// R4: R3's top kernel was the f32 vector-ALU GEMM (45.6us, VALUBusy 34%,
// occupancy 18%, 3.4M LDS bank conflicts). Replace both GEMMs with
// mfma_f32_16x16x32_bf16: A-frags loaded directly from global bf16 (16B/lane),
// W pre-packed into B-fragment order (L2-resident), no LDS, ~50 VGPR.
// x and h are stored bf16 (outputs already were); all accumulation f32.
// CSR build (counting sort, LDS atomics) and spmm gathers unchanged from R3.
// NOTE: packing assumes N < 65536 (row/col fit 16 bits). N = 50000 here.
// ---------------------------------------------------------------------------

#define WS_ALIGN(x) (((x) + 255) & ~((size_t)255))

typedef __attribute__((ext_vector_type(8))) short short8;
typedef __attribute__((ext_vector_type(4))) float floatx4;

__device__ __forceinline__ unsigned short f2bf(float f) {
    unsigned u = __float_as_uint(f);
    u += 0x7fffu + ((u >> 16) & 1u);          // round-to-nearest-even
    return (unsigned short)(u >> 16);
}
__device__ __forceinline__ float bf2f(unsigned short h) {
    return __uint_as_float(((unsigned)h) << 16);
}
__device__ __forceinline__ float sigmoidf(float x) {
    return 1.f / (1.f + __expf(-x));
}

static const int NBLK = 256;   // blocks for binning passes
#define MAXNB 256              // max coarse buckets supported (N <= 65536)

// ---------------------------------------------------------------------------
// CSR build: 2-level counting sort, LDS atomics only.
// ---------------------------------------------------------------------------
__launch_bounds__(256)
__global__ void binA_count(const int* __restrict__ row, int* __restrict__ bucket_count,
                           int* __restrict__ bases, int E, int chunk, int NB)
{
    __shared__ int hist[MAXNB];
    const int t = threadIdx.x;
    const int blk = blockIdx.x;
    if (t < NB) hist[t] = 0;
    __syncthreads();
    const int s = blk * chunk;
    const int e = min(E, s + chunk);
    for (int i = s + t; i < e; i += 256)
        atomicAdd(&hist[row[i] >> 8], 1);
    __syncthreads();
    if (t < NB)
        bases[blk * NB + t] = atomicAdd(&bucket_count[t], hist[t]);
}

__launch_bounds__(256)
__global__ void bin_scan(const int* __restrict__ bucket_count, int* __restrict__ bucket_start,
                         int NB)
{
    __shared__ int s[256];
    const int t = threadIdx.x;
    int v = (t < NB) ? bucket_count[t] : 0;
    s[t] = v;
    __syncthreads();
    for (int off = 1; off < 256; off <<= 1) {
        int u = (t >= off) ? s[t - off] : 0;
        __syncthreads();
        s[t] += u;
        __syncthreads();
    }
    int excl = s[t] - v;
    if (t <= NB) bucket_start[t] = excl;   // t==NB: total == E
}

__launch_bounds__(256)
__global__ void binA_scatter(const int* __restrict__ row, const int* __restrict__ colv,
                             const float* __restrict__ ea,
                             const int* __restrict__ bucket_start, const int* __restrict__ bases,
                             int2* __restrict__ bk, int E, int chunk, int NB)
{
    __shared__ int cur[MAXNB];
    const int t = threadIdx.x;
    const int blk = blockIdx.x;
    if (t < NB) cur[t] = bucket_start[t] + bases[blk * NB + t];
    __syncthreads();
    const int s = blk * chunk;
    const int e = min(E, s + chunk);
    for (int i = s + t; i < e; i += 256) {
        int r = row[i];
        int bin = r >> 8;
        int pos = atomicAdd(&cur[bin], 1);
        bk[pos] = make_int2(((r & 255) << 16) | colv[i], __float_as_int(ea[i]));
    }
}

__launch_bounds__(256)
__global__ void binB(const int2* __restrict__ bk, const int* __restrict__ bucket_start,
                     int* __restrict__ rowptr, int2* __restrict__ edges, int N)
{
    __shared__ int cnt[256];
    __shared__ float deg[256];
    __shared__ float inv[256];
    __shared__ int excl_s[256];
    __shared__ int cur[256];
    __shared__ int scantmp[256];
    const int b = blockIdx.x;
    const int t = threadIdx.x;
    const int s = bucket_start[b];
    const int e = bucket_start[b + 1];
    cnt[t] = 0;
    deg[t] = 0.f;
    __syncthreads();
    for (int i = s + t; i < e; i += 256) {
        int2 v = bk[i];
        int rl = ((unsigned)v.x) >> 16;
        atomicAdd(&cnt[rl], 1);
        atomicAdd(&deg[rl], __int_as_float(v.y));
    }
    __syncthreads();
    const int myc = cnt[t];
    scantmp[t] = myc;
    __syncthreads();
    for (int off = 1; off < 256; off <<= 1) {
        int u = (t >= off) ? scantmp[t - off] : 0;
        __syncthreads();
        scantmp[t] += u;
        __syncthreads();
    }
    const int excl = scantmp[t] - myc;
    excl_s[t] = excl;
    float d = deg[t];
    inv[t] = (d > 0.f) ? 1.f / d : 0.f;
    cur[t] = 0;
    const int gr = b * 256 + t;
    if (gr <= N) rowptr[gr] = s + excl;
    __syncthreads();
    for (int i = s + t; i < e; i += 256) {
        int2 v = bk[i];
        int rl = ((unsigned)v.x) >> 16;
        int c = v.x & 0xffff;
        int p = s + excl_s[rl] + atomicAdd(&cur[rl], 1);
        edges[p] = make_int2(c, __float_as_int(__int_as_float(v.y) * inv[rl]));
    }
}

// ---------------------------------------------------------------------------
// Conversions / packing
// ---------------------------------------------------------------------------
__global__ void f32_to_bf16_kernel(const float* __restrict__ in, unsigned short* __restrict__ out,
                                   int n2)  // n2 = n/2 pairs
{
    int i = blockIdx.x * 256 + threadIdx.x;
    if (i < n2) {
        float2 v = ((const float2*)in)[i];
        unsigned p = (unsigned)f2bf(v.x) | ((unsigned)f2bf(v.y) << 16);
        ((unsigned*)out)[i] = p;
    }
}

// Pre-pack W[128,COLS] f32 -> bf16 in MFMA B-fragment order.
// frag index idx = (ct*4 + t)*64 + lane; element j: W[t*32 + (lane>>4)*8 + j][ct*16 + (lane&15)]
template<int COLS>
__global__ void pack_w_kernel(const float* __restrict__ W, unsigned short* __restrict__ Wp)
{
    const int total = (COLS / 16) * 4 * 64;
    int idx = blockIdx.x * 256 + threadIdx.x;
    if (idx >= total) return;
    const int l = idx & 63;
    const int t = (idx >> 6) & 3;
    const int ct = idx >> 8;
    const int kbase = t * 32 + (l >> 4) * 8;
    const int col = ct * 16 + (l & 15);
    unsigned short v[8];
#pragma unroll
    for (int j = 0; j < 8; ++j)
        v[j] = f2bf(W[(size_t)(kbase + j) * COLS + col]);
    uint4 o;
    o.x = (unsigned)v[0] | ((unsigned)v[1] << 16);
    o.y = (unsigned)v[2] | ((unsigned)v[3] << 16);
    o.z = (unsigned)v[4] | ((unsigned)v[5] << 16);
    o.w = (unsigned)v[6] | ((unsigned)v[7] << 16);
    *(uint4*)(Wp + (size_t)idx * 8) = o;
}

// ---------------------------------------------------------------------------
// MFMA GEMM: C_bf16[M,COLS] = A_bf16[M,128] @ W[128,COLS] (Wp pre-packed).
// 4 waves/block, wave = 16 rows x COLS, K=128 in 4 k-tiles. No LDS.
// ---------------------------------------------------------------------------
template<int COLS>
__launch_bounds__(256)
__global__ void gemm_mfma(const unsigned short* __restrict__ A,
                          const unsigned short* __restrict__ Wp,
                          unsigned short* __restrict__ C, int M)
{
    const int wave = threadIdx.x >> 6;
    const int lane = threadIdx.x & 63;
    const int row0 = blockIdx.x * 64 + wave * 16;
    const int m = lane & 15;
    const int q = lane >> 4;

    const int arow = row0 + m;
    const bool avalid = arow < M;
    short8 a[4];
#pragma unroll
    for (int t = 0; t < 4; ++t) {
        if (avalid)
            a[t] = *(const short8*)(A + (size_t)arow * 128 + t * 32 + q * 8);
        else
            a[t] = (short8)0;
    }

#pragma unroll
    for (int ct = 0; ct < COLS / 16; ++ct) {
        floatx4 acc = {0.f, 0.f, 0.f, 0.f};
#pragma unroll
        for (int t = 0; t < 4; ++t) {
            short8 b = *(const short8*)(Wp + (size_t)((ct * 4 + t) * 64 + lane) * 8);
            acc = __builtin_amdgcn_mfma_f32_16x16x32_bf16(a[t], b, acc, 0, 0, 0);
        }
        const int col = ct * 16 + m;
#pragma unroll
        for (int r = 0; r < 4; ++r) {
            int orow = row0 + q * 4 + r;
            if (orow < M)
                C[(size_t)orow * COLS + col] = f2bf(acc[r]);
        }
    }
}

// ---------------------------------------------------------------------------
// SpMM F=128, bf16 src, bias+relu, bf16 packed output. One wave/row.
// ---------------------------------------------------------------------------
__launch_bounds__(256)
__global__ void spmm128_relu(const int* __restrict__ rowptr, const int2* __restrict__ edges,
                             const unsigned short* __restrict__ src,
                             const float* __restrict__ bias, unsigned* __restrict__ out, int n)
{
    const int row = blockIdx.x * 4 + (threadIdx.x >> 6);
    const int lane = threadIdx.x & 63;
    if (row >= n) return;
    const int s = rowptr[row];
    const int e = rowptr[row + 1];
    const unsigned* us = (const unsigned*)src;   // 64 uints / row

    float ax[8], ay[8];
#pragma unroll
    for (int j = 0; j < 8; ++j) { ax[j] = 0.f; ay[j] = 0.f; }
    int i = s;
    for (; i + 8 <= e; i += 8) {
        int2 ed[8];
        unsigned u[8];
#pragma unroll
        for (int j = 0; j < 8; ++j) ed[j] = edges[i + j];
#pragma unroll
        for (int j = 0; j < 8; ++j) u[j] = us[(size_t)ed[j].x * 64 + lane];
#pragma unroll
        for (int j = 0; j < 8; ++j) {
            float w = __int_as_float(ed[j].y);
            ax[j] = fmaf(w, __uint_as_float(u[j] << 16), ax[j]);
            ay[j] = fmaf(w, __uint_as_float(u[j] & 0xffff0000u), ay[j]);
        }
    }
    for (; i + 4 <= e; i += 4) {
        int2 ed[4];
        unsigned u[4];
#pragma unroll
        for (int j = 0; j < 4; ++j) ed[j] = edges[i + j];
#pragma unroll
        for (int j = 0; j < 4; ++j) u[j] = us[(size_t)ed[j].x * 64 + lane];
#pragma unroll
        for (int j = 0; j < 4; ++j) {
            float w = __int_as_float(ed[j].y);
            ax[j] = fmaf(w, __uint_as_float(u[j] << 16), ax[j]);
            ay[j] = fmaf(w, __uint_as_float(u[j] & 0xffff0000u), ay[j]);
        }
    }
    for (; i < e; ++i) {
        int2 e0 = edges[i];
        unsigned u0 = us[(size_t)e0.x * 64 + lane];
        float w0 = __int_as_float(e0.y);
        ax[0] = fmaf(w0, __uint_as_float(u0 << 16), ax[0]);
        ay[0] = fmaf(w0, __uint_as_float(u0 & 0xffff0000u), ay[0]);
    }
    float vx = ((ax[0] + ax[1]) + (ax[2] + ax[3])) + ((ax[4] + ax[5]) + (ax[6] + ax[7]));
    float vy = ((ay[0] + ay[1]) + (ay[2] + ay[3])) + ((ay[4] + ay[5]) + (ay[6] + ay[7]));
    float2 b = *(const float2*)(bias + lane * 2);
    vx = fmaxf(vx + b.x, 0.f);
    vy = fmaxf(vy + b.y, 0.f);
    out[(size_t)row * 64 + lane] = (unsigned)f2bf(vx) | ((unsigned)f2bf(vy) << 16);
}

// ---------------------------------------------------------------------------
// SpMM F=64, bf16 src. ACT: 0 none, 2 bias+sigmoid, 3 sigmoid.
// OUT_BF16: store bf16 (LPA intermediates) else f32.
// ---------------------------------------------------------------------------
template<int ACT, bool OUT_BF16>
__launch_bounds__(256)
__global__ void spmm64_kernel(const int* __restrict__ rowptr, const int2* __restrict__ edges,
                              const unsigned short* __restrict__ src,
                              const float* __restrict__ bias, void* __restrict__ out, int n)
{
    const int row = blockIdx.x * 4 + (threadIdx.x >> 6);
    const int lane = threadIdx.x & 63;
    if (row >= n) return;
    const int s = rowptr[row];
    const int e = rowptr[row + 1];

    float a[8];
#pragma unroll
    for (int j = 0; j < 8; ++j) a[j] = 0.f;
    int i = s;
    for (; i + 8 <= e; i += 8) {
        int2 ed[8];
        float sv[8];
#pragma unroll
        for (int j = 0; j < 8; ++j) ed[j] = edges[i + j];
#pragma unroll
        for (int j = 0; j < 8; ++j) sv[j] = bf2f(src[(size_t)ed[j].x * 64 + lane]);
#pragma unroll
        for (int j = 0; j < 8; ++j) a[j] = fmaf(__int_as_float(ed[j].y), sv[j], a[j]);
    }
    for (; i + 4 <= e; i += 4) {
        int2 ed[4];
        float sv[4];
#pragma unroll
        for (int j = 0; j < 4; ++j) ed[j] = edges[i + j];
#pragma unroll
        for (int j = 0; j < 4; ++j) sv[j] = bf2f(src[(size_t)ed[j].x * 64 + lane]);
#pragma unroll
        for (int j = 0; j < 4; ++j) a[j] = fmaf(__int_as_float(ed[j].y), sv[j], a[j]);
    }
    for (; i < e; ++i) {
        int2 e0 = edges[i];
        a[0] = fmaf(__int_as_float(e0.y), bf2f(src[(size_t)e0.x * 64 + lane]), a[0]);
    }
    float v = ((a[0] + a[1]) + (a[2] + a[3])) + ((a[4] + a[5]) + (a[6] + a[7]));
    if (ACT == 2) v = sigmoidf(v + bias[lane]);
    else if (ACT == 3) v = sigmoidf(v);
    if (OUT_BF16)
        ((unsigned short*)out)[(size_t)row * 64 + lane] = f2bf(v);
    else
        ((float*)out)[(size_t)row * 64 + lane] = v;
}

// ---------------------------------------------------------------------------
extern "C" void kernel_launch(void* const* d_in, const int* in_sizes, int n_in,
                              void* d_out, int out_size, void* d_ws, size_t ws_size,
                              hipStream_t stream)
{
    const float* x    = (const float*)d_in[0];
    const float* soft = (const float*)d_in[1];
    const float* ea   = (const float*)d_in[2];
    const float* w1   = (const float*)d_in[3];
    const float* b1   = (const float*)d_in[4];
    const float* w2   = (const float*)d_in[5];
    const float* b2   = (const float*)d_in[6];
    const int*   eidx = (const int*)d_in[7];

    const int N = in_sizes[0] / 128;
    const int E = in_sizes[2];
    const int* row  = eidx;
    const int* colv = eidx + E;
    const int NB = (N + 255) / 256;            // coarse buckets (<= 256)
    const int chunk = (E + NBLK - 1) / NBLK;

    uint8_t* ws = (uint8_t*)d_ws;
    size_t off = 0;
    auto alloc = [&](size_t bytes) -> void* {
        void* p = ws + off;
        off += WS_ALIGN(bytes);
        return p;
    };
    int*  bucket_count = (int*) alloc((size_t)NB * 4);
    int*  bucket_start = (int*) alloc(((size_t)NB + 1) * 4);
    int*  bases        = (int*) alloc((size_t)NBLK * NB * 4);
    int*  rowptr       = (int*) alloc(((size_t)N + 1) * 4);
    int2* bk           = (int2*)alloc((size_t)E * 8);
    int2* edges        = (int2*)alloc((size_t)E * 8);
    unsigned short* xb      = (unsigned short*)alloc((size_t)N * 128 * 2);
    unsigned short* w1p     = (unsigned short*)alloc((size_t)128 * 128 * 2);
    unsigned short* w2p     = (unsigned short*)alloc((size_t)128 * 64 * 2);
    unsigned short* xw1b    = (unsigned short*)alloc((size_t)N * 128 * 2);
    unsigned short* hb      = (unsigned short*)alloc((size_t)N * 128 * 2);
    unsigned short* logitsb = (unsigned short*)alloc((size_t)N * 64 * 2);
    unsigned short* softb   = (unsigned short*)alloc((size_t)N * 64 * 2);
    unsigned short* labA    = (unsigned short*)alloc((size_t)N * 64 * 2);
    unsigned short* labB    = (unsigned short*)alloc((size_t)N * 64 * 2);

    float* out0 = (float*)d_out;             // x_out [N,64]
    float* out1 = out0 + (size_t)N * 64;     // labels [N,64]

    hipMemsetAsync(bucket_count, 0, (size_t)NB * 4, stream);

    // CSR build: counting sort, LDS atomics only (+50k block-level globals)
    binA_count<<<NBLK, 256, 0, stream>>>(row, bucket_count, bases, E, chunk, NB);
    bin_scan<<<1, 256, 0, stream>>>(bucket_count, bucket_start, NB);
    binA_scatter<<<NBLK, 256, 0, stream>>>(row, colv, ea, bucket_start, bases, bk, E, chunk, NB);
    binB<<<NB, 256, 0, stream>>>(bk, bucket_start, rowptr, edges, N);

    // conversions: x, soft -> bf16; w1, w2 -> packed bf16 fragments
    const int nx2 = (N * 128) / 2;
    f32_to_bf16_kernel<<<(nx2 + 255) / 256, 256, 0, stream>>>(x, xb, nx2);
    const int ns2 = (N * 64) / 2;
    f32_to_bf16_kernel<<<(ns2 + 255) / 256, 256, 0, stream>>>(soft, softb, ns2);
    pack_w_kernel<128><<<8, 256, 0, stream>>>(w1, w1p);
    pack_w_kernel<64><<<4, 256, 0, stream>>>(w2, w2p);

    const int gGemm = (N + 63) / 64;
    const int gSp   = (N + 3) / 4;

    gemm_mfma<128><<<gGemm, 256, 0, stream>>>(xb, w1p, xw1b, N);                   // xw1 (bf16)
    spmm128_relu<<<gSp, 256, 0, stream>>>(rowptr, edges, xw1b, b1, (unsigned*)hb, N); // h (bf16)
    gemm_mfma<64><<<gGemm, 256, 0, stream>>>(hb, w2p, logitsb, N);                 // logits (bf16)
    spmm64_kernel<2, false><<<gSp, 256, 0, stream>>>(rowptr, edges, logitsb, b2, out0, N);

    spmm64_kernel<0, true ><<<gSp, 256, 0, stream>>>(rowptr, edges, softb, nullptr, labA, N);
    spmm64_kernel<0, true ><<<gSp, 256, 0, stream>>>(rowptr, edges, labA, nullptr, labB, N);
    spmm64_kernel<0, true ><<<gSp, 256, 0, stream>>>(rowptr, edges, labB, nullptr, labA, N);
    spmm64_kernel<0, true ><<<gSp, 256, 0, stream>>>(rowptr, edges, labA, nullptr, labB, N);
    spmm64_kernel<3, false><<<gSp, 256, 0, stream>>>(rowptr, edges, labB, nullptr, out1, N);
}